// Round 4
// baseline (412.233 us; speedup 1.0000x reference)
//
#include <hip/hip_runtime.h>

#define NL 64  // NUM_LABELS

// Phase 1: VALU-only binning. 64 register accumulators per lane; per element,
// compare against all 64 labels (cmp+cndmask+add = 3 VALU). Sum and count are
// FOLDED into one f32: acc += (lab==q) ? (1 + val*2^-12) : 0, so per-bin value
// is count + sum*2^-12. Unfolded per block (count = rint, |sum|*2^-12 << 0.5).
// No LDS in the hot loop -> sidesteps the ~108 cyc/instr LDS-atomic ceiling
// measured in R1-R3.
__global__ __launch_bounds__(256, 4) void tl_reduce(const float* __restrict__ tex,
                                                    const int* __restrict__ lab,
                                                    float* __restrict__ g_sums,
                                                    unsigned int* __restrict__ g_cnts,
                                                    int n) {
    float acc[NL];
    #pragma unroll
    for (int q = 0; q < NL; ++q) acc[q] = 0.0f;

    const int n4 = n >> 2;
    const float4* __restrict__ tex4 = (const float4*)tex;
    const int4* __restrict__ lab4 = (const int4*)lab;
    const int stride = gridDim.x * 256;
    const float K = 1.0f / 4096.0f;  // fold scale 2^-12
    const int tid = threadIdx.x;

    int i = blockIdx.x * 256 + tid;
    bool v = i < n4;
    float4 t; int4 l;
    if (v) { t = tex4[i]; l = lab4[i]; }
    while (v) {
        const int inext = i + stride;
        const bool vn = inext < n4;
        float4 tn; int4 ln;
        if (vn) { tn = tex4[inext]; ln = lab4[inext]; }

        const float vx = fmaf(t.x, K, 1.0f);
        const float vy = fmaf(t.y, K, 1.0f);
        const float vz = fmaf(t.z, K, 1.0f);
        const float vw = fmaf(t.w, K, 1.0f);
        const int lx = l.x & (NL - 1), ly = l.y & (NL - 1);
        const int lz = l.z & (NL - 1), lw = l.w & (NL - 1);
        #pragma unroll
        for (int q = 0; q < NL; ++q) {
            acc[q] += (lx == q) ? vx : 0.0f;
            acc[q] += (ly == q) ? vy : 0.0f;
            acc[q] += (lz == q) ? vz : 0.0f;
            acc[q] += (lw == q) ? vw : 0.0f;
        }
        i = inext; v = vn; t = tn; l = ln;
    }

    // scalar tail (n % 4), block 0 only (n is divisible by 4 here; kept for safety)
    if (blockIdx.x == 0) {
        const int base = n4 << 2;
        const int rem = n - base;
        if (tid < rem) {
            const int j = base + tid;
            const float vt = fmaf(tex[j], K, 1.0f);
            const int lt = lab[j] & (NL - 1);
            #pragma unroll
            for (int q = 0; q < NL; ++q) acc[q] += (lt == q) ? vt : 0.0f;
        }
    }

    // Block reduction: one-time LDS pass (cheap vs the hot loop).
    __shared__ float s_red[NL * NL];   // [label][col], 16 KB
    __shared__ float s_part[256];
    const int col = tid & (NL - 1);

    for (int k = tid; k < NL * NL; k += 256) s_red[k] = 0.0f;
    __syncthreads();
    #pragma unroll
    for (int q = 0; q < NL; ++q)
        atomicAdd(&s_red[(q << 6) | col], acc[q]);   // 4 waves share columns
    __syncthreads();

    // thread t: label = t&63, quarter w = t>>6 sums 16 columns (diagonal).
    {
        const int label = tid & (NL - 1);
        const int w = tid >> 6;
        float s = 0.0f;
        #pragma unroll
        for (int k = 0; k < 16; ++k)
            s += s_red[(label << 6) | (w << 4) | ((k + tid) & 15)];
        s_part[tid] = s;
    }
    __syncthreads();

    if (tid < NL) {
        const float T = s_part[tid] + s_part[64 + tid] + s_part[128 + tid] + s_part[192 + tid];
        const float C = rintf(T);               // exact per-block count
        const float S = (T - C) * 4096.0f;      // unfolded per-block sum
        atomicAdd(&g_sums[tid], S);
        atomicAdd(&g_cnts[tid], (unsigned int)C);
    }
}

// Phase 2: build delta table in LDS (label 0 -> 0), apply out = tex - delta[lab].
__global__ __launch_bounds__(256) void tl_apply(const float* __restrict__ tex,
                                                const int* __restrict__ lab,
                                                const float* __restrict__ g_sums,
                                                const unsigned int* __restrict__ g_cnts,
                                                const float* __restrict__ intens,
                                                float* __restrict__ out, int n) {
    __shared__ float s_delta[NL];
    if (threadIdx.x < NL) {
        const int l = threadIdx.x;
        const float mean = g_sums[l] / fmaxf((float)g_cnts[l], 1.0f);
        s_delta[l] = (l > 0) ? (mean - intens[l]) : 0.0f;
    }
    __syncthreads();

    const int n4 = n >> 2;
    const int i = blockIdx.x * blockDim.x + threadIdx.x;
    if (i < n4) {
        const float4 t = ((const float4*)tex)[i];
        const int4 l = ((const int4*)lab)[i];
        float4 o;
        o.x = t.x - s_delta[l.x & (NL - 1)];
        o.y = t.y - s_delta[l.y & (NL - 1)];
        o.z = t.z - s_delta[l.z & (NL - 1)];
        o.w = t.w - s_delta[l.w & (NL - 1)];
        ((float4*)out)[i] = o;
    }
    if (blockIdx.x == 0) {
        const int base = n4 << 2;
        const int rem = n - base;
        if ((int)threadIdx.x < rem) {
            const int j = base + threadIdx.x;
            out[j] = tex[j] - s_delta[lab[j] & (NL - 1)];
        }
    }
}

extern "C" void kernel_launch(void* const* d_in, const int* in_sizes, int n_in,
                              void* d_out, int out_size, void* d_ws, size_t ws_size,
                              hipStream_t stream) {
    const float* tex    = (const float*)d_in[0];
    const int*   lab    = (const int*)d_in[1];
    const float* intens = (const float*)d_in[2];
    float* out = (float*)d_out;
    const int n = in_sizes[0];

    float* g_sums = (float*)d_ws;
    unsigned int* g_cnts = (unsigned int*)((char*)d_ws + NL * sizeof(float));

    // d_ws is re-poisoned to 0xAA before every timed launch — zero the bins.
    hipMemsetAsync(d_ws, 0, 2 * NL * sizeof(float), stream);

    // Phase 1: 2048 blocks x 256 threads, 12 float4 per thread.
    tl_reduce<<<2048, 256, 0, stream>>>(tex, lab, g_sums, g_cnts, n);

    // Phase 2: one float4 per thread.
    const int n4 = n >> 2;
    const int blocks = (n4 + 255) / 256;
    tl_apply<<<blocks, 256, 0, stream>>>(tex, lab, g_sums, g_cnts, intens, out, n);
}